// Round 12
// baseline (392.111 us; speedup 1.0000x reference)
//
#include <hip/hip_runtime.h>
#include <hip/hip_fp16.h>

#define NDIM 8192
#define KDIM 8192
#define NT 256          // N / 32 hash tiles
#define MOD2 4193281    // HASH_SIZE - 32*32 + 1
#define PRIME 2038074743LL

#define BM 128
#define BN 128
#define KITER 64        // (KDIM/4)/32, split-K = 4
#define ASTRIDE 40      // halves per A row (32 + 8 pad)
#define BSLAB 1032      // halves per k-octet slab (128*8 + 8 pad)

typedef _Float16 half8 __attribute__((ext_vector_type(8)));
typedef __fp16 fp16x2 __attribute__((ext_vector_type(2)));
typedef float floatx4 __attribute__((ext_vector_type(4)));

// LDS-only barrier: drains ds ops but leaves global prefetch loads in flight.
#define BARRIER() asm volatile("s_waitcnt lgkmcnt(0)\n\ts_barrier" ::: "memory")

static __device__ __forceinline__ unsigned pkrtz(float a, float b) {
    fp16x2 h = __builtin_amdgcn_cvt_pkrtz(a, b);
    unsigned u;
    __builtin_memcpy(&u, &h, 4);
    return u;
}

// ---------------- prepass: out = bias, ROBE-Z starts (no cvt anymore) ----------------
__global__ __launch_bounds__(256) void prep_kernel(const float* __restrict__ bias,
                                                   const int* __restrict__ rn,
                                                   int* __restrict__ starts,
                                                   float* __restrict__ out) {
    int b = blockIdx.x;
    int tid = threadIdx.x;
    if (b < 4096) {                       // init: out = bias (atomic targets)
        int i = b * 256 + tid;
        float4 bv = *(const float4*)(bias + ((i & 2047) << 2));
        ((float4*)out)[i] = bv;
    } else {                              // starts: 64K hash tile offsets
        int t = (b - 4096) * 256 + tid;
        bool is64 = (rn[1] == 0 && rn[3] == 0);   // int64 input: words 1,3 are hi-halves
        long long R1 = is64 ? rn[2] : rn[1];
        long long R2 = is64 ? rn[4] : rn[2];
        long long R3 = is64 ? rn[6] : rn[3];
        long long k_id = t >> 8, n_id = t & 255;
        long long v = (k_id * R3 + n_id * R2 + R1) % PRIME;
        starts[t] = (int)(v % MOD2);
    }
}

// ---------------- main GEMM: split-K=4, 128x128 block, staging direct from f32 ----------------
__global__ __launch_bounds__(256, 4) void gemm_kernel(
    const float* __restrict__ x, const float* __restrict__ hw,
    const int* __restrict__ starts, float* __restrict__ out) {
    __shared__ __align__(16) __half As[2][BM * ASTRIDE];   // [m][k] padded, f16
    __shared__ __align__(16) __half Bs[2][4 * BSLAB];      // [k-octet][n][8] k-runs, f16
    __shared__ int Ss[KITER * 4];                          // per-block starts table

    const int tid = threadIdx.x;
    const int lane = tid & 63;
    const int wave = tid >> 6;       // 0..3
    const int wm = wave >> 1;        // 0..1 : 64-row strip
    const int wn = wave & 1;         // 0..1 : 64-col strip
    const int quad = lane >> 4;
    const int l16 = lane & 15;

    const int i = blockIdx.x;        // 1024 blocks
    const int ks = i & 3;
    const int m_blk = (i >> 2) & 3;
    const int n_blk = i >> 4;        // 0..63
    const int gm0 = m_blk * BM;
    const int gn0 = n_blk * BN;
    const int kt0 = ks * KITER;
    const int n_id0 = n_blk * 4;     // 4 hash tiles per block

    Ss[tid] = starts[(kt0 + (tid >> 2)) * NT + n_id0 + (tid & 3)];  // 256 = KITER*4

    // A staging: thread covers row tid>>1, 16-elem chunk (tid&1)
    const int a_row = tid >> 1;               // 0..127
    const int a_ch = tid & 1;
    const float* aptr = x + (size_t)(gm0 + a_row) * KDIM + kt0 * 32 + a_ch * 16;
    const unsigned a_woff = a_row * ASTRIDE + a_ch * 16;

    // B staging: thread owns hash tile (tid>>6), k-octet ((tid>>4)&3), n-pair (tid&15)
    const int b_tile = tid >> 6;              // 0..3
    const int b_oct = (tid >> 4) & 3;         // 0..3
    const int b_np = tid & 15;                // n-pair
    const unsigned b_woff = b_oct * BSLAB + (b_tile * 32 + 2 * b_np) * 8;

    // prefetch registers: A dist-1 single set (f32x4 x4); B dist-2 two STATIC float2 sets
    float4 fa0, fa1, fa2, fa3;
    float2 gE0, gE1, gE2, gE3, gE4, gE5, gE6, gE7;
    float2 gO0, gO1, gO2, gO3, gO4, gO5, gO6, gO7;

#define LOADA(kp_) do {                                                        \
        fa0 = *(const float4*)(aptr + (kp_) * 32);                             \
        fa1 = *(const float4*)(aptr + (kp_) * 32 + 4);                         \
        fa2 = *(const float4*)(aptr + (kp_) * 32 + 8);                         \
        fa3 = *(const float4*)(aptr + (kp_) * 32 + 12);                        \
    } while (0)

#define LOADB(G0, G1, G2, G3, G4, G5, G6, G7, kp_) do {                        \
        int st = Ss[(kp_) * 4 + b_tile];                                       \
        const float* src = hw + st + b_oct * 256 + b_np * 2;                   \
        G0 = *(const float2*)(src);                                            \
        G1 = *(const float2*)(src + 32);                                       \
        G2 = *(const float2*)(src + 64);                                       \
        G3 = *(const float2*)(src + 96);                                       \
        G4 = *(const float2*)(src + 128);                                      \
        G5 = *(const float2*)(src + 160);                                      \
        G6 = *(const float2*)(src + 192);                                      \
        G7 = *(const float2*)(src + 224);                                      \
    } while (0)

#define STORET(G0, G1, G2, G3, G4, G5, G6, G7, buf_) do {                      \
        uint4 wa0 = {pkrtz(fa0.x, fa0.y), pkrtz(fa0.z, fa0.w),                 \
                     pkrtz(fa1.x, fa1.y), pkrtz(fa1.z, fa1.w)};                \
        uint4 wa1 = {pkrtz(fa2.x, fa2.y), pkrtz(fa2.z, fa2.w),                 \
                     pkrtz(fa3.x, fa3.y), pkrtz(fa3.z, fa3.w)};                \
        *(uint4*)&As[buf_][a_woff] = wa0;                                      \
        *(uint4*)&As[buf_][a_woff + 8] = wa1;                                  \
        uint4 we = {pkrtz(G0.x, G1.x), pkrtz(G2.x, G3.x),                      \
                    pkrtz(G4.x, G5.x), pkrtz(G6.x, G7.x)};                     \
        uint4 wo = {pkrtz(G0.y, G1.y), pkrtz(G2.y, G3.y),                      \
                    pkrtz(G4.y, G5.y), pkrtz(G6.y, G7.y)};                     \
        *(uint4*)&Bs[buf_][b_woff] = we;                                       \
        *(uint4*)&Bs[buf_][b_woff + 8] = wo;                                   \
    } while (0)

    floatx4 acc[4][4];
#pragma unroll
    for (int r = 0; r < 4; r++)
#pragma unroll
        for (int c = 0; c < 4; c++)
            acc[r][c] = (floatx4){0.f, 0.f, 0.f, 0.f};

#define FRAGS_MFMA(buf_) do {                                                  \
        half8 af[4], bf[4];                                                    \
        _Pragma("unroll")                                                      \
        for (int r = 0; r < 4; r++)                                            \
            af[r] = *(const half8*)&As[buf_][(wm * 64 + r * 16 + l16) * ASTRIDE + quad * 8]; \
        _Pragma("unroll")                                                      \
        for (int c = 0; c < 4; c++)                                            \
            bf[c] = *(const half8*)&Bs[buf_][quad * BSLAB + (wn * 64 + c * 16 + l16) * 8];   \
        _Pragma("unroll")                                                      \
        for (int r = 0; r < 4; r++)                                            \
            _Pragma("unroll")                                                  \
            for (int c = 0; c < 4; c++)                                        \
                acc[r][c] = __builtin_amdgcn_mfma_f32_16x16x32_f16(af[r], bf[c], acc[r][c], 0, 0, 0); \
    } while (0)

    BARRIER();                        // Ss visible
    LOADB(gE0, gE1, gE2, gE3, gE4, gE5, gE6, gE7, 0);   // B(0) -> set E
    LOADB(gO0, gO1, gO2, gO3, gO4, gO5, gO6, gO7, 1);   // B(1) -> set O
    LOADA(0);
    STORET(gE0, gE1, gE2, gE3, gE4, gE5, gE6, gE7, 0);  // tile 0 -> buf0
    BARRIER();

    for (int kp = 0; kp < KITER; kp += 2) {
        // even half: compute tile kp (buf0)
        LOADA(kp + 1);                                   // A(kp+1), dist-1
        if (kp + 2 < KITER)
            LOADB(gE0, gE1, gE2, gE3, gE4, gE5, gE6, gE7, kp + 2);  // B(kp+2), dist-2
        FRAGS_MFMA(0);
        STORET(gO0, gO1, gO2, gO3, gO4, gO5, gO6, gO7, 1);          // tile kp+1 -> buf1
        BARRIER();

        // odd half: compute tile kp+1 (buf1)
        if (kp + 2 < KITER) {
            LOADA(kp + 2);
            if (kp + 3 < KITER)
                LOADB(gO0, gO1, gO2, gO3, gO4, gO5, gO6, gO7, kp + 3);
        }
        FRAGS_MFMA(1);
        if (kp + 2 < KITER)
            STORET(gE0, gE1, gE2, gE3, gE4, gE5, gE6, gE7, 0);      // tile kp+2 -> buf0
        BARRIER();
    }

    // ---- epilogue: atomic accumulate (C/D layout col=lane&15, row=quad*4+reg) ----
#pragma unroll
    for (int c = 0; c < 4; c++) {
        int col = gn0 + wn * 64 + c * 16 + l16;
#pragma unroll
        for (int r = 0; r < 4; r++) {
            int row0 = gm0 + wm * 64 + r * 16 + quad * 4;
#pragma unroll
            for (int e = 0; e < 4; e++)
                atomicAdd(&out[(size_t)(row0 + e) * NDIM + col], acc[r][c][e]);
        }
    }
#undef LOADA
#undef LOADB
#undef STORET
#undef FRAGS_MFMA
}

extern "C" void kernel_launch(void* const* d_in, const int* in_sizes, int n_in,
                              void* d_out, int out_size, void* d_ws, size_t ws_size,
                              hipStream_t stream) {
    const float* x = (const float*)d_in[0];
    const float* hw = (const float*)d_in[1];
    const float* bias = (const float*)d_in[2];
    const int* rn = (const int*)d_in[3];
    float* out = (float*)d_out;

    int* starts = (int*)d_ws;                          // 256 KB : tile start table

    hipLaunchKernelGGL(prep_kernel, dim3(4352), dim3(256), 0, stream,
                       bias, rn, starts, out);
    hipLaunchKernelGGL(gemm_kernel, dim3(1024), dim3(256), 0, stream, x, hw, starts, out);
}